// Round 3
// baseline (1081.801 us; speedup 1.0000x reference)
//
#include <hip/hip_runtime.h>
#include <hip/hip_bf16.h>

typedef __hip_bfloat16 bf16;
typedef __attribute__((ext_vector_type(8))) short short8;   // 8 x bf16 (4 VGPRs)
typedef __attribute__((ext_vector_type(4))) float f32x4;

#define Hdim 512
#define Bdim 512
#define Tdim 64
#define Fdim 64
#define NC   4

__device__ __forceinline__ float sigmoidf_(float x){ return 1.f/(1.f + __expf(-x)); }
__device__ __forceinline__ float tanhf_(float x){
  float t = __expf(-2.f*fabsf(x));
  float r = (1.f - t)/(1.f + t);
  return copysignf(r, x);
}
__device__ __forceinline__ float bf2f_(short u){
  return __uint_as_float(((unsigned)(unsigned short)u) << 16);
}
__device__ __forceinline__ short f2bf_(float f){
  bf16 b = (bf16)f;
  return *(short*)&b;
}

// ---------------- fp32 -> bf16 pack (fc_in_W only) ----------------
__global__ __launch_bounds__(256) void pack_kernel(const float* __restrict__ src,
                                                   bf16* __restrict__ dst, int n){
  int idx = (blockIdx.x*256 + threadIdx.x)*4;
  if (idx < n){
    float4 v = *(const float4*)(src + idx);
    dst[idx+0] = (bf16)v.x;
    dst[idx+1] = (bf16)v.y;
    dst[idx+2] = (bf16)v.z;
    dst[idx+3] = (bf16)v.w;
  }
}

// ---------------- transpose data [B][F][T] fp32 -> dataT [T][B][F] bf16 ----------------
__global__ __launch_bounds__(256) void transpose_kernel(const float* __restrict__ data,
                                                        bf16* __restrict__ dataT){
  __shared__ bf16 tile[64*65];
  int b = blockIdx.x;
  int tid = threadIdx.x;
  for (int i = 0; i < 16; ++i){
    int idx = tid + i*256;
    int f = idx >> 6, t = idx & 63;
    tile[f*65 + t] = (bf16)data[(b*64 + f)*64 + t];
  }
  __syncthreads();
  for (int i = 0; i < 16; ++i){
    int idx = tid + i*256;
    int t = idx >> 6, f = idx & 63;
    dataT[(t*Bdim + b)*64 + f] = tile[f*65 + t];
  }
}

// ---------------- init: h(-1) bf16 shadow, owner-major 16-col chunks ----------------
// layout: [ (k*2+bt)*32 + chunk ][ b_local(256) ][ 16 ]
__global__ __launch_bounds__(256) void init_kernel(const float* __restrict__ init_h,
                            bf16* __restrict__ h_b1, unsigned* __restrict__ flags){
  int idx = blockIdx.x*256 + threadIdx.x;          // 0 .. 4*512*512-1
  int k = idx >> 18;
  int rem = idx & 262143;                          // b_glob*512 + o
  int bg = rem >> 9;
  int o  = rem & 511;
  int dst = ((k*2 + (bg >> 8))*32 + (o >> 4))*4096 + (bg & 255)*16 + (o & 15);
  h_b1[dst] = (bf16)init_h[rem];
  if (idx < 512) flags[idx] = 0u;                  // flags[8][32] + xslot[8][32]
}

// ---------------- input projection: x_seq[s][k][b][h] = relu(dataT[src_t] @ fc_in_W[k]^T + b)
__global__ __launch_bounds__(256) void proj_kernel(const bf16* __restrict__ dataT,
    const bf16* __restrict__ fc_in_W, const float* __restrict__ fc_in_b,
    bf16* __restrict__ x_seq){
  __shared__ short ldsA[64*72];
  __shared__ short ldsW[128*72];
  int blk = blockIdx.x;
  int s  = blk >> 7;
  int k  = (blk >> 5) & 3;
  int bt = (blk >> 2) & 7;
  int on = blk & 3;
  int tid = threadIdx.x;
  int lane = tid & 63, wid = tid >> 6;
  int quad = lane >> 4, l16 = lane & 15;
  int src_t = (k < 2) ? s : (Tdim - 1 - s);

  const short* Ag = (const short*)(dataT + (src_t*Bdim + bt*64)*Fdim);
  #pragma unroll
  for (int i = 0; i < 2; ++i){
    int c = tid + i*256; int r = c >> 3, off = c & 7;
    *(int4*)(&ldsA[r*72 + off*8]) = *(const int4*)(&Ag[r*64 + off*8]);
  }
  const short* Wg = (const short*)(fc_in_W + (k*Hdim + on*128)*Fdim);
  #pragma unroll
  for (int i = 0; i < 4; ++i){
    int c = tid + i*256; int r = c >> 3, off = c & 7;
    *(int4*)(&ldsW[r*72 + off*8]) = *(const int4*)(&Wg[r*64 + off*8]);
  }
  __syncthreads();

  f32x4 acc[2][4];
  #pragma unroll
  for (int nt=0; nt<2; ++nt)
    #pragma unroll
    for (int rb=0; rb<4; ++rb) acc[nt][rb] = (f32x4){0.f,0.f,0.f,0.f};

  #pragma unroll
  for (int kk = 0; kk < 2; ++kk){
    int io = kk*32 + quad*8;
    short8 a[4];
    #pragma unroll
    for (int rb=0; rb<4; ++rb) a[rb] = *(const short8*)(&ldsA[(rb*16+l16)*72 + io]);
    #pragma unroll
    for (int nt=0; nt<2; ++nt){
      short8 bw = *(const short8*)(&ldsW[(wid*32 + nt*16 + l16)*72 + io]);
      #pragma unroll
      for (int rb=0; rb<4; ++rb)
        acc[nt][rb] = __builtin_amdgcn_mfma_f32_16x16x32_bf16(a[rb], bw, acc[nt][rb], 0,0,0);
    }
  }

  #pragma unroll
  for (int nt=0; nt<2; ++nt){
    int o = on*128 + wid*32 + nt*16 + l16;
    float bias = fc_in_b[k*Hdim + o];
    #pragma unroll
    for (int rb=0; rb<4; ++rb){
      #pragma unroll
      for (int reg=0; reg<4; ++reg){
        int b = bt*64 + rb*16 + quad*4 + reg;
        float v = acc[nt][rb][reg] + bias;
        v = v > 0.f ? v : 0.f;
        x_seq[((size_t)(s*NC + k)*Bdim + b)*Hdim + o] = (bf16)v;
      }
    }
  }
}

// ---------------- persistent GRU, r16: intra-CU producer/consumer wave split ----
// One 1024-thread block per CU (LDS 144 KB forces 1/CU; grid 256). Waves 0-7 =
// producer role (x@Wih^T for this CU's N=16 o-tile), waves 8-15 = consumer role
// (h@Whh^T + gates + h update for the SAME o-tile). Why:
//  (1) r13/r15 showed MFMA busy-time is design-invariant (~180us); the rest is
//      stall. Producer waves are an independent instruction stream on the same
//      SIMDs: while consumer waves spin on cross-CU h-flags / wait on h loads,
//      producer MFMAs + x loads issue (m114: separate streams co-schedule).
//  (2) gi handoff is intra-CU via a depth-2 LDS ring (48 KB): no L2 round trip,
//      no producer flag domain (r15 confirmed: WRITE_SIZE 568->220 MB).
//  (3) All intra-block sync is LDS acquire/release counters -- no block-wide
//      barrier after init, so a waiting role never drags the other.
//  (4) s_setprio(1) around the consumer h-GEMM: role-split waves are exactly
//      the regime where setprio pays (T5).
// Cross-CU remains only the fundamental h all-to-all: 32 flags/XCD, consumer
// wave 8 polls, LDS-broadcasts readiness; per-wave vmcnt(0) drain + last-
// arriver counter replaces r13's __syncthreads-then-flag.
__global__ __launch_bounds__(1024) void rnn_kernel(
    const bf16* __restrict__ x_seq, const float* __restrict__ init_h,
    bf16* __restrict__ h_b0, bf16* __restrict__ h_b1,
    const float* __restrict__ Wih, const float* __restrict__ Whh,
    const float* __restrict__ bih, const float* __restrict__ bhh,
    const float* __restrict__ fc_out_W,
    float* __restrict__ part,
    unsigned* __restrict__ flags, unsigned* __restrict__ xslot)
{
  __shared__ short wlds[2*3*16*512];     // 96 KB weights: [side2][gate3][kc16][lane64] x8 bf16
  __shared__ short glds[2*12288];        // 48 KB gi ring: [slot2][(g*2+rb)*8+w][lane][reg4] bf16
  __shared__ unsigned gprod[2], gcons[2], hready, hdone;
  __shared__ int sslot;

  int tid = threadIdx.x;
  int lane = tid & 63, wid = tid >> 6;          // wid 0..15
  int quad = lane >> 4, l16 = lane & 15;
  int wrow = wid & 7;                           // row-group within role

  // ---- physical-XCD self-assignment (1 block/CU pigeonhole via 144KB LDS) ----
  unsigned xcc;
  asm volatile("s_getreg_b32 %0, hwreg(HW_REG_XCC_ID)" : "=s"(xcc));
  xcc &= 7u;
  if (tid == 0){
    sslot = (int)__hip_atomic_fetch_add(&xslot[xcc*32], 1u,
                __ATOMIC_RELAXED, __HIP_MEMORY_SCOPE_WORKGROUP);
    gprod[0] = gprod[1] = gcons[0] = gcons[1] = 0u;
    hready = 0u; hdone = 0u;
  }
  __syncthreads();
  int grp = (int)xcc;
  int k   = grp >> 1;
  int bt  = grp & 1;
  int j   = sslot & 31;                // o-tile 0..31 (16 cols each)
  int rot = j & 15;                    // K-ring phase stagger
  unsigned* gflags = flags + grp*32;   // 32 h-flags for this group

  // ---- both weight sides -> LDS once, fp32->bf16, B-fragment lane order ----
  for (int i = tid; i < 6144; i += 1024){
    int side = (i >= 3072);
    int i2   = i - side*3072;
    int plane = i2 >> 10;
    int rem2  = i2 & 1023;
    int kc    = rem2 >> 6;
    int ln    = rem2 & 63;
    int ll16  = ln & 15, lq = ln >> 4;
    const float* Wsrc = side ? Whh : Wih;
    const float* srcp = Wsrc +
        ((size_t)(k*3 + plane)*Hdim + j*16 + ll16)*Hdim + kc*32 + lq*8;
    float4 f0 = *(const float4*)srcp;
    float4 f1 = *(const float4*)(srcp + 4);
    short8 pk;
    pk[0]=f2bf_(f0.x); pk[1]=f2bf_(f0.y); pk[2]=f2bf_(f0.z); pk[3]=f2bf_(f0.w);
    pk[4]=f2bf_(f1.x); pk[5]=f2bf_(f1.y); pk[6]=f2bf_(f1.z); pk[7]=f2bf_(f1.w);
    *(int4*)(&wlds[i*8]) = *(int4*)&pk;
  }

  // ---- consumer-only per-thread constants + fp32 h state ----
  int o0 = j*16 + l16;
  float br=0.f, bz=0.f, bnx=0.f, bnh=0.f, wout=0.f;
  float hk[2][4];
  if (wid >= 8){
    br  = bih[k*3*Hdim + o0] + bhh[k*3*Hdim + o0];
    bz  = bih[k*3*Hdim + Hdim + o0] + bhh[k*3*Hdim + Hdim + o0];
    bnx = bih[k*3*Hdim + 2*Hdim + o0];
    bnh = bhh[k*3*Hdim + 2*Hdim + o0];
    wout = fc_out_W[(k & 1)*Hdim + o0];
    #pragma unroll
    for (int rb=0; rb<2; ++rb)
      #pragma unroll
      for (int reg=0; reg<4; ++reg)
        hk[rb][reg] =
          init_h[(bt*256 + wrow*32 + rb*16 + quad*4 + reg)*Hdim + o0];
  }

  const size_t hgbase = (size_t)((k*2 + bt)*32) * 4096;  // group h base (shorts)

  __syncthreads();   // LDS weights ready; LAST block-wide barrier.

  // x-GEMM: A rows stride Hdim, K-chunk c at col offset c*32. Wih = side 0.
  #define GEMM16X(ABASE, ACC) do {                                              \
    _Pragma("unroll")                                                           \
    for (int g=0; g<3; ++g){ ACC[g][0] = (f32x4){0.f,0.f,0.f,0.f};              \
                             ACC[g][1] = (f32x4){0.f,0.f,0.f,0.f}; }            \
    const short* ap0_ = (ABASE) + (wrow*32 + l16)*Hdim + quad*8;                \
    const short* ap1_ = ap0_ + 16*Hdim;                                         \
    short8 ab_[4][2];                                                           \
    _Pragma("unroll")                                                           \
    for (int d=0; d<4; ++d){                                                    \
      int c_ = (d + rot) & 15;                                                  \
      ab_[d][0] = *(const short8*)(ap0_ + c_*32);                               \
      ab_[d][1] = *(const short8*)(ap1_ + c_*32);                               \
    }                                                                           \
    short8 bb_[2][3];                                                           \
    _Pragma("unroll")                                                           \
    for (int g=0; g<3; ++g)                                                     \
      bb_[0][g] = *(const short8*)(&wlds[((g*16 + rot)<<9) + (lane<<3)]);       \
    _Pragma("unroll")                                                           \
    for (int kc=0; kc<16; ++kc){                                                \
      short8 a0_ = ab_[kc&3][0], a1_ = ab_[kc&3][1];                            \
      if (kc < 12){                                                             \
        int c_ = (kc + 4 + rot) & 15;                                           \
        ab_[kc&3][0] = *(const short8*)(ap0_ + c_*32);                          \
        ab_[kc&3][1] = *(const short8*)(ap1_ + c_*32);                          \
      }                                                                         \
      if (kc < 15){                                                             \
        int c_ = (kc + 1 + rot) & 15;                                           \
        _Pragma("unroll")                                                       \
        for (int g=0; g<3; ++g)                                                 \
          bb_[(kc+1)&1][g] = *(const short8*)(&wlds[((g*16 + c_)<<9) + (lane<<3)]); \
      }                                                                         \
      _Pragma("unroll")                                                         \
      for (int g=0; g<3; ++g){                                                  \
        short8 bw_ = bb_[kc&1][g];                                              \
        ACC[g][0] = __builtin_amdgcn_mfma_f32_16x16x32_bf16(a0_, bw_, ACC[g][0], 0,0,0); \
        ACC[g][1] = __builtin_amdgcn_mfma_f32_16x16x32_bf16(a1_, bw_, ACC[g][1], 0,0,0); \
      }                                                                         \
    }                                                                           \
  } while(0)

  // h-GEMM: owner-major 16-col chunks; K32 chunk c spans owner chunks {2c,2c+1}.
  #define GEMM16H(HCB, ACC) do {                                                \
    _Pragma("unroll")                                                           \
    for (int g=0; g<3; ++g){ ACC[g][0] = (f32x4){0.f,0.f,0.f,0.f};              \
                             ACC[g][1] = (f32x4){0.f,0.f,0.f,0.f}; }            \
    const short* hp0_ = (HCB) + (quad>>1)*4096 + (wrow*32 + l16)*16 + (quad&1)*8;\
    const short* hp1_ = hp0_ + 256;                                             \
    short8 ab_[4][2];                                                           \
    _Pragma("unroll")                                                           \
    for (int d=0; d<4; ++d){                                                    \
      int c_ = (d + rot) & 15;                                                  \
      ab_[d][0] = *(const short8*)(hp0_ + c_*8192);                             \
      ab_[d][1] = *(const short8*)(hp1_ + c_*8192);                             \
    }                                                                           \
    short8 bb_[2][3];                                                           \
    _Pragma("unroll")                                                           \
    for (int g=0; g<3; ++g)                                                     \
      bb_[0][g] = *(const short8*)(&wlds[(((3+g)*16 + rot)<<9) + (lane<<3)]);   \
    _Pragma("unroll")                                                           \
    for (int kc=0; kc<16; ++kc){                                                \
      short8 a0_ = ab_[kc&3][0], a1_ = ab_[kc&3][1];                            \
      if (kc < 12){                                                             \
        int c_ = (kc + 4 + rot) & 15;                                           \
        ab_[kc&3][0] = *(const short8*)(hp0_ + c_*8192);                        \
        ab_[kc&3][1] = *(const short8*)(hp1_ + c_*8192);                        \
      }                                                                         \
      if (kc < 15){                                                             \
        int c_ = (kc + 1 + rot) & 15;                                           \
        _Pragma("unroll")                                                       \
        for (int g=0; g<3; ++g)                                                 \
          bb_[(kc+1)&1][g] = *(const short8*)(&wlds[(((3+g)*16 + c_)<<9) + (lane<<3)]); \
      }                                                                         \
      _Pragma("unroll")                                                         \
      for (int g=0; g<3; ++g){                                                  \
        short8 bw_ = bb_[kc&1][g];                                              \
        ACC[g][0] = __builtin_amdgcn_mfma_f32_16x16x32_bf16(a0_, bw_, ACC[g][0], 0,0,0); \
        ACC[g][1] = __builtin_amdgcn_mfma_f32_16x16x32_bf16(a1_, bw_, ACC[g][1], 0,0,0); \
      }                                                                         \
    }                                                                           \
  } while(0)

  if (wid < 8){
    // ================= PRODUCER role: gi(t) -> LDS ring slot t&1 =================
    for (int t = 0; t < 64; ++t){
      if (t >= 2){
        // WAR: consumers must have finished reading gi(t-2) from this slot
        unsigned tgt = 8u * (unsigned)(t >> 1);
        int g_ = 0;
        while (__hip_atomic_load(&gcons[t & 1], __ATOMIC_ACQUIRE,
                                 __HIP_MEMORY_SCOPE_WORKGROUP) < tgt){
          __builtin_amdgcn_s_sleep(1);
          if (++g_ > 8000000) break;
        }
      }
      f32x4 acc[3][2];
      const short* xb_ = (const short*)(x_seq +
          ((size_t)(t*NC + k)*Bdim + bt*256)*Hdim);
      GEMM16X(xb_, acc);
      // pack f32x4 -> 4 bf16, one 8B LDS write per (g,rb)
      int gbase = (t & 1)*12288;
      #pragma unroll
      for (int g = 0; g < 3; ++g){
        #pragma unroll
        for (int rb = 0; rb < 2; ++rb){
          unsigned lo = ((unsigned)(unsigned short)f2bf_(acc[g][rb][0])) |
                        (((unsigned)(unsigned short)f2bf_(acc[g][rb][1])) << 16);
          unsigned hi = ((unsigned)(unsigned short)f2bf_(acc[g][rb][2])) |
                        (((unsigned)(unsigned short)f2bf_(acc[g][rb][3])) << 16);
          int idx = gbase + (((g*2 + rb)*8 + wrow)*64 + lane)*4;
          int2 pk; pk.x = (int)lo; pk.y = (int)hi;
          *(int2*)(&glds[idx]) = pk;
        }
      }
      if (lane == 0)
        __hip_atomic_fetch_add(&gprod[t & 1], 1u,
                               __ATOMIC_RELEASE, __HIP_MEMORY_SCOPE_WORKGROUP);
    }
  } else {
    // ================= CONSUMER role: recurrence for o-tile j =================
    for (int s = 0; s < 64; ++s){
      const bf16* h_in  = (s & 1) ? h_b0 : h_b1;
      bf16*       h_out = (s & 1) ? h_b1 : h_b0;

      // cross-CU rendezvous: wave 8 polls the 32 group flags, broadcasts via LDS
      if (wid == 8){
        int g_ = 0;
        for (;;){
          unsigned v_ = 0xFFFFFFFFu;
          if (lane < 32)
            v_ = __hip_atomic_load(&gflags[lane], __ATOMIC_RELAXED,
                                   __HIP_MEMORY_SCOPE_AGENT);
          if (__ballot(v_ >= (unsigned)s) == ~0ull) break;
          __builtin_amdgcn_s_sleep(1);
          if (++g_ > 8000000) break;
        }
        if (lane == 0)
          __hip_atomic_store(&hready, (unsigned)(s + 1),
                             __ATOMIC_RELEASE, __HIP_MEMORY_SCOPE_WORKGROUP);
      } else {
        int g_ = 0;
        while (__hip_atomic_load(&hready, __ATOMIC_ACQUIRE,
                                 __HIP_MEMORY_SCOPE_WORKGROUP) < (unsigned)(s + 1)){
          __builtin_amdgcn_s_sleep(1);
          if (++g_ > 8000000) break;
        }
      }

      f32x4 hacc[3][2];
      __builtin_amdgcn_s_setprio(1);
      GEMM16H((const short*)h_in + hgbase, hacc);
      __builtin_amdgcn_s_setprio(0);

      // gi(s) from LDS ring (producers run ~1 step ahead; near-instant)
      {
        unsigned tgt = 8u * (unsigned)((s >> 1) + 1);
        int g_ = 0;
        while (__hip_atomic_load(&gprod[s & 1], __ATOMIC_ACQUIRE,
                                 __HIP_MEMORY_SCOPE_WORKGROUP) < tgt){
          __builtin_amdgcn_s_sleep(1);
          if (++g_ > 8000000) break;
        }
      }
      float gv[3][2][4];
      {
        int gbase = (s & 1)*12288;
        #pragma unroll
        for (int g = 0; g < 3; ++g){
          #pragma unroll
          for (int rb = 0; rb < 2; ++rb){
            int idx = gbase + (((g*2 + rb)*8 + wrow)*64 + lane)*4;
            int2 t2 = *(const int2*)(&glds[idx]);
            gv[g][rb][0] = bf2f_((short)(t2.x & 0xFFFF));
            gv[g][rb][1] = bf2f_((short)((unsigned)t2.x >> 16));
            gv[g][rb][2] = bf2f_((short)(t2.y & 0xFFFF));
            gv[g][rb][3] = bf2f_((short)((unsigned)t2.y >> 16));
          }
        }
      }

      // gates, register h update, h store
      bf16* hob = h_out + hgbase + (size_t)j*4096;
      #pragma unroll
      for (int rb = 0; rb < 2; ++rb){
        #pragma unroll
        for (int reg = 0; reg < 4; ++reg){
          int bl = wrow*32 + rb*16 + quad*4 + reg;
          float r = sigmoidf_(gv[0][rb][reg] + hacc[0][rb][reg] + br);
          float z = sigmoidf_(gv[1][rb][reg] + hacc[1][rb][reg] + bz);
          float n = tanhf_(gv[2][rb][reg] + bnx + r*(hacc[2][rb][reg] + bnh));
          float hn = (1.f - z)*n + z*hk[rb][reg];
          hk[rb][reg] = hn;
          hob[bl*16 + l16] = (bf16)hn;
        }
      }

      // signal gi-read done (frees the ring slot for t = s+2)
      if (lane == 0)
        __hip_atomic_fetch_add(&gcons[s & 1], 1u,
                               __ATOMIC_RELEASE, __HIP_MEMORY_SCOPE_WORKGROUP);

      // per-wave store drain; last-arriving wave bumps the group flag
      asm volatile("s_waitcnt vmcnt(0)" ::: "memory");
      if (lane == 0){
        unsigned old = __hip_atomic_fetch_add(&hdone, 1u,
                          __ATOMIC_ACQ_REL, __HIP_MEMORY_SCOPE_WORKGROUP);
        if (old == (unsigned)(8*s + 7))
          __hip_atomic_fetch_add(&gflags[j], 1u,
                                 __ATOMIC_RELAXED, __HIP_MEMORY_SCOPE_AGENT);
      }

      // off-critical-path: output head partial dot
      int tmap = (k < 2) ? s : (Tdim - 1 - s);
      #pragma unroll
      for (int rb = 0; rb < 2; ++rb){
        #pragma unroll
        for (int reg = 0; reg < 4; ++reg){
          int bl = wrow*32 + rb*16 + quad*4 + reg;
          float v = hk[rb][reg]*wout;
          v += __shfl_xor(v, 1, 64);
          v += __shfl_xor(v, 2, 64);
          v += __shfl_xor(v, 4, 64);
          v += __shfl_xor(v, 8, 64);
          if (l16 == 0)
            __builtin_nontemporal_store(v,
              &part[((size_t)(k*Tdim + tmap)*Bdim + bt*256 + bl)*32 + j]);
        }
      }
    }
  }
  #undef GEMM16X
  #undef GEMM16H
}

// ---------------- out[head][b][t] = bias + sum over {head,head+2} x 32 j-partials ----
// part layout [K][T][B][32]: per-thread reads are 128 B contiguous.
__global__ __launch_bounds__(256) void finalize_kernel(const float* __restrict__ part,
                                const float* __restrict__ fc_out_b, float* __restrict__ out){
  int idx = blockIdx.x*256 + threadIdx.x;  // 0..65535
  int head = idx >> 15;
  int b = (idx >> 6) & 511;
  int t = idx & 63;
  float v = fc_out_b[head];
  #pragma unroll
  for (int kk = 0; kk < 2; ++kk){
    const float4* p = (const float4*)(part +
        ((size_t)((head + kk*2)*Tdim + t)*Bdim + b)*32);
    #pragma unroll
    for (int jj = 0; jj < 8; ++jj){
      float4 q = p[jj];
      v += q.x + q.y + q.z + q.w;
    }
  }
  out[idx] = v;
}

extern "C" void kernel_launch(void* const* d_in, const int* in_sizes, int n_in,
                              void* d_out, int out_size, void* d_ws, size_t ws_size,
                              hipStream_t stream){
  (void)in_sizes; (void)n_in; (void)out_size; (void)ws_size;
  const float* data     = (const float*)d_in[0];
  const float* init_h   = (const float*)d_in[1];
  const float* fc_in_W  = (const float*)d_in[2];
  const float* fc_in_b  = (const float*)d_in[3];
  const float* Wih      = (const float*)d_in[4];
  const float* Whh      = (const float*)d_in[5];
  const float* bih      = (const float*)d_in[6];
  const float* bhh      = (const float*)d_in[7];
  const float* fc_out_W = (const float*)d_in[8];
  const float* fc_out_b = (const float*)d_in[9];
  float* out = (float*)d_out;

  char* ws = (char*)d_ws;
  bf16*  x_seq   = (bf16*)ws;                     // [T][K][B][H] bf16 : 134217728 B
  bf16*  h_b0    = (bf16*)(ws + 134217728);       // [grp*32+c][b][16] :  2097152 B
  bf16*  h_b1    = (bf16*)(ws + 136314880);       //                      2097152 B
  float* part    = (float*)(ws + 138412032);      // [K][T][B][32] f32: 16777216 B
  bf16*  dataT   = (bf16*)(ws + 138412032);       // overlay (dead before rnn): 4 MB
  bf16*  fcW_bf  = (bf16*)(ws + 165675008);       // [K][H][F] bf16 :      262144 B
  unsigned* flags= (unsigned*)(ws + 165937152);   // [8][32] u32 = 1024 B
  unsigned* xslot= (unsigned*)(ws + 165938176);   // [8][32] u32 = 1024 B

  const int nFW = NC*Hdim*Fdim;     // 131,072
  hipLaunchKernelGGL(pack_kernel, dim3(nFW/1024), dim3(256), 0, stream, fc_in_W, fcW_bf, nFW);
  hipLaunchKernelGGL(init_kernel, dim3(4096), dim3(256), 0, stream, init_h, h_b1, flags);
  hipLaunchKernelGGL(transpose_kernel, dim3(512), dim3(256), 0, stream, data, dataT);
  hipLaunchKernelGGL(proj_kernel, dim3(8192), dim3(256), 0, stream, dataT, fcW_bf, fc_in_b, x_seq);
  hipLaunchKernelGGL(rnn_kernel, dim3(256), dim3(1024), 0, stream,
      x_seq, init_h, h_b0, h_b1, Wih, Whh, bih, bhh, fc_out_W, part, flags, xslot);
  hipLaunchKernelGGL(finalize_kernel, dim3(256), dim3(256), 0, stream, part, fc_out_b, out);
}

// Round 4
// 970.967 us; speedup vs baseline: 1.1141x; 1.1141x over previous
//
#include <hip/hip_runtime.h>
#include <hip/hip_bf16.h>

typedef __hip_bfloat16 bf16;
typedef __attribute__((ext_vector_type(8))) short short8;   // 8 x bf16 (4 VGPRs)
typedef __attribute__((ext_vector_type(4))) float f32x4;

#define Hdim 512
#define Bdim 512
#define Tdim 64
#define Fdim 64
#define NC   4

__device__ __forceinline__ float sigmoidf_(float x){ return 1.f/(1.f + __expf(-x)); }
__device__ __forceinline__ float tanhf_(float x){
  float t = __expf(-2.f*fabsf(x));
  float r = (1.f - t)/(1.f + t);
  return copysignf(r, x);
}
__device__ __forceinline__ float bf2f_(short u){
  return __uint_as_float(((unsigned)(unsigned short)u) << 16);
}
__device__ __forceinline__ short f2bf_(float f){
  bf16 b = (bf16)f;
  return *(short*)&b;
}

// ---------------- fp32 -> bf16 pack (fc_in_W only) ----------------
__global__ __launch_bounds__(256) void pack_kernel(const float* __restrict__ src,
                                                   bf16* __restrict__ dst, int n){
  int idx = (blockIdx.x*256 + threadIdx.x)*4;
  if (idx < n){
    float4 v = *(const float4*)(src + idx);
    dst[idx+0] = (bf16)v.x;
    dst[idx+1] = (bf16)v.y;
    dst[idx+2] = (bf16)v.z;
    dst[idx+3] = (bf16)v.w;
  }
}

// ---------------- transpose data [B][F][T] fp32 -> dataT [T][B][F] bf16 ----------------
__global__ __launch_bounds__(256) void transpose_kernel(const float* __restrict__ data,
                                                        bf16* __restrict__ dataT){
  __shared__ bf16 tile[64*65];
  int b = blockIdx.x;
  int tid = threadIdx.x;
  for (int i = 0; i < 16; ++i){
    int idx = tid + i*256;
    int f = idx >> 6, t = idx & 63;
    tile[f*65 + t] = (bf16)data[(b*64 + f)*64 + t];
  }
  __syncthreads();
  for (int i = 0; i < 16; ++i){
    int idx = tid + i*256;
    int t = idx >> 6, f = idx & 63;
    dataT[(t*Bdim + b)*64 + f] = tile[f*65 + t];
  }
}

// ---------------- init: h(-1) bf16 shadow, owner-major 16-col chunks ----------------
// layout: [ (k*2+bt)*32 + chunk ][ b_local(256) ][ 16 ]
__global__ __launch_bounds__(256) void init_kernel(const float* __restrict__ init_h,
                            bf16* __restrict__ h_b1, unsigned* __restrict__ flags){
  int idx = blockIdx.x*256 + threadIdx.x;          // 0 .. 4*512*512-1
  int k = idx >> 18;
  int rem = idx & 262143;                          // b_glob*512 + o
  int bg = rem >> 9;
  int o  = rem & 511;
  int dst = ((k*2 + (bg >> 8))*32 + (o >> 4))*4096 + (bg & 255)*16 + (o & 15);
  h_b1[dst] = (bf16)init_h[rem];
  if (idx < 512) flags[idx] = 0u;                  // flags[8][32] + xslot[8][32]
}

// ---------------- input projection: x_seq[s][k][b][h] = relu(dataT[src_t] @ fc_in_W[k]^T + b)
__global__ __launch_bounds__(256) void proj_kernel(const bf16* __restrict__ dataT,
    const bf16* __restrict__ fc_in_W, const float* __restrict__ fc_in_b,
    bf16* __restrict__ x_seq){
  __shared__ short ldsA[64*72];
  __shared__ short ldsW[128*72];
  int blk = blockIdx.x;
  int s  = blk >> 7;
  int k  = (blk >> 5) & 3;
  int bt = (blk >> 2) & 7;
  int on = blk & 3;
  int tid = threadIdx.x;
  int lane = tid & 63, wid = tid >> 6;
  int quad = lane >> 4, l16 = lane & 15;
  int src_t = (k < 2) ? s : (Tdim - 1 - s);

  const short* Ag = (const short*)(dataT + (src_t*Bdim + bt*64)*Fdim);
  #pragma unroll
  for (int i = 0; i < 2; ++i){
    int c = tid + i*256; int r = c >> 3, off = c & 7;
    *(int4*)(&ldsA[r*72 + off*8]) = *(const int4*)(&Ag[r*64 + off*8]);
  }
  const short* Wg = (const short*)(fc_in_W + (k*Hdim + on*128)*Fdim);
  #pragma unroll
  for (int i = 0; i < 4; ++i){
    int c = tid + i*256; int r = c >> 3, off = c & 7;
    *(int4*)(&ldsW[r*72 + off*8]) = *(const int4*)(&Wg[r*64 + off*8]);
  }
  __syncthreads();

  f32x4 acc[2][4];
  #pragma unroll
  for (int nt=0; nt<2; ++nt)
    #pragma unroll
    for (int rb=0; rb<4; ++rb) acc[nt][rb] = (f32x4){0.f,0.f,0.f,0.f};

  #pragma unroll
  for (int kk = 0; kk < 2; ++kk){
    int io = kk*32 + quad*8;
    short8 a[4];
    #pragma unroll
    for (int rb=0; rb<4; ++rb) a[rb] = *(const short8*)(&ldsA[(rb*16+l16)*72 + io]);
    #pragma unroll
    for (int nt=0; nt<2; ++nt){
      short8 bw = *(const short8*)(&ldsW[(wid*32 + nt*16 + l16)*72 + io]);
      #pragma unroll
      for (int rb=0; rb<4; ++rb)
        acc[nt][rb] = __builtin_amdgcn_mfma_f32_16x16x32_bf16(a[rb], bw, acc[nt][rb], 0,0,0);
    }
  }

  #pragma unroll
  for (int nt=0; nt<2; ++nt){
    int o = on*128 + wid*32 + nt*16 + l16;
    float bias = fc_in_b[k*Hdim + o];
    #pragma unroll
    for (int rb=0; rb<4; ++rb){
      #pragma unroll
      for (int reg=0; reg<4; ++reg){
        int b = bt*64 + rb*16 + quad*4 + reg;
        float v = acc[nt][rb][reg] + bias;
        v = v > 0.f ? v : 0.f;
        x_seq[((size_t)(s*NC + k)*Bdim + b)*Hdim + o] = (bf16)v;
      }
    }
  }
}

// ---------------- persistent GRU, r17: r16 intra-CU wave split, VGPR FIXED ----
// r16's regression root-caused: __launch_bounds__(1024) let the compiler cap at
// 64 VGPR/wave -> the GEMM register working set (~100) spilled to scratch
// (VGPR_Count=64, MfmaUtil 17%). r17 declares (1024, 4): 16 waves/block = 4
// waves/EU at 1 block/CU -> 128 VGPR budget, same allocation r13 proved fits.
// Register-pressure assists: consumer keeps gi packed (int2[3][2], 12 VGPR,
// unpack inside the unrolled epilogue); gcons release moves right after the gi
// LDS reads drain (lgkmcnt(0)), off the producer WAR chain.
// Design recap (r16, numerically verified): waves 0-7 produce x@Wih^T for this
// CU's N=16 o-tile into a depth-2 LDS gi ring; waves 8-15 run h@Whh^T + gates
// + h update for the same tile. Producer waves are an independent instruction
// stream that fills consumer stall cycles (m114); setprio(1) wraps the h-GEMM
// (T5 role-split regime). Cross-CU sync = 32 h-flags/XCD, polled by wave 8,
// LDS-broadcast; per-wave vmcnt(0) + last-arriver counter bumps the flag.
__global__ __launch_bounds__(1024, 4) void rnn_kernel(
    const bf16* __restrict__ x_seq, const float* __restrict__ init_h,
    bf16* __restrict__ h_b0, bf16* __restrict__ h_b1,
    const float* __restrict__ Wih, const float* __restrict__ Whh,
    const float* __restrict__ bih, const float* __restrict__ bhh,
    const float* __restrict__ fc_out_W,
    float* __restrict__ part,
    unsigned* __restrict__ flags, unsigned* __restrict__ xslot)
{
  __shared__ short wlds[2*3*16*512];     // 96 KB weights: [side2][gate3][kc16][lane64] x8 bf16
  __shared__ short glds[2*12288];        // 48 KB gi ring: [slot2][(g*2+rb)*8+w][lane][reg4] bf16
  __shared__ unsigned gprod[2], gcons[2], hready, hdone;
  __shared__ int sslot;

  int tid = threadIdx.x;
  int lane = tid & 63, wid = tid >> 6;          // wid 0..15
  int quad = lane >> 4, l16 = lane & 15;
  int wrow = wid & 7;                           // row-group within role

  // ---- physical-XCD self-assignment (1 block/CU pigeonhole via 144KB LDS) ----
  unsigned xcc;
  asm volatile("s_getreg_b32 %0, hwreg(HW_REG_XCC_ID)" : "=s"(xcc));
  xcc &= 7u;
  if (tid == 0){
    sslot = (int)__hip_atomic_fetch_add(&xslot[xcc*32], 1u,
                __ATOMIC_RELAXED, __HIP_MEMORY_SCOPE_WORKGROUP);
    gprod[0] = gprod[1] = gcons[0] = gcons[1] = 0u;
    hready = 0u; hdone = 0u;
  }
  __syncthreads();
  int grp = (int)xcc;
  int k   = grp >> 1;
  int bt  = grp & 1;
  int j   = sslot & 31;                // o-tile 0..31 (16 cols each)
  int rot = j & 15;                    // K-ring phase stagger
  unsigned* gflags = flags + grp*32;   // 32 h-flags for this group

  // ---- both weight sides -> LDS once, fp32->bf16, B-fragment lane order ----
  for (int i = tid; i < 6144; i += 1024){
    int side = (i >= 3072);
    int i2   = i - side*3072;
    int plane = i2 >> 10;
    int rem2  = i2 & 1023;
    int kc    = rem2 >> 6;
    int ln    = rem2 & 63;
    int ll16  = ln & 15, lq = ln >> 4;
    const float* Wsrc = side ? Whh : Wih;
    const float* srcp = Wsrc +
        ((size_t)(k*3 + plane)*Hdim + j*16 + ll16)*Hdim + kc*32 + lq*8;
    float4 f0 = *(const float4*)srcp;
    float4 f1 = *(const float4*)(srcp + 4);
    short8 pk;
    pk[0]=f2bf_(f0.x); pk[1]=f2bf_(f0.y); pk[2]=f2bf_(f0.z); pk[3]=f2bf_(f0.w);
    pk[4]=f2bf_(f1.x); pk[5]=f2bf_(f1.y); pk[6]=f2bf_(f1.z); pk[7]=f2bf_(f1.w);
    *(int4*)(&wlds[i*8]) = *(int4*)&pk;
  }

  // ---- consumer-only per-thread constants + fp32 h state ----
  int o0 = j*16 + l16;
  float br=0.f, bz=0.f, bnx=0.f, bnh=0.f, wout=0.f;
  float hk[2][4];
  if (wid >= 8){
    br  = bih[k*3*Hdim + o0] + bhh[k*3*Hdim + o0];
    bz  = bih[k*3*Hdim + Hdim + o0] + bhh[k*3*Hdim + Hdim + o0];
    bnx = bih[k*3*Hdim + 2*Hdim + o0];
    bnh = bhh[k*3*Hdim + 2*Hdim + o0];
    wout = fc_out_W[(k & 1)*Hdim + o0];
    #pragma unroll
    for (int rb=0; rb<2; ++rb)
      #pragma unroll
      for (int reg=0; reg<4; ++reg)
        hk[rb][reg] =
          init_h[(bt*256 + wrow*32 + rb*16 + quad*4 + reg)*Hdim + o0];
  }

  const size_t hgbase = (size_t)((k*2 + bt)*32) * 4096;  // group h base (shorts)

  __syncthreads();   // LDS weights ready; LAST block-wide barrier.

  // x-GEMM: A rows stride Hdim, K-chunk c at col offset c*32. Wih = side 0.
  #define GEMM16X(ABASE, ACC) do {                                              \
    _Pragma("unroll")                                                           \
    for (int g=0; g<3; ++g){ ACC[g][0] = (f32x4){0.f,0.f,0.f,0.f};              \
                             ACC[g][1] = (f32x4){0.f,0.f,0.f,0.f}; }            \
    const short* ap0_ = (ABASE) + (wrow*32 + l16)*Hdim + quad*8;                \
    const short* ap1_ = ap0_ + 16*Hdim;                                         \
    short8 ab_[4][2];                                                           \
    _Pragma("unroll")                                                           \
    for (int d=0; d<4; ++d){                                                    \
      int c_ = (d + rot) & 15;                                                  \
      ab_[d][0] = *(const short8*)(ap0_ + c_*32);                               \
      ab_[d][1] = *(const short8*)(ap1_ + c_*32);                               \
    }                                                                           \
    short8 bb_[2][3];                                                           \
    _Pragma("unroll")                                                           \
    for (int g=0; g<3; ++g)                                                     \
      bb_[0][g] = *(const short8*)(&wlds[((g*16 + rot)<<9) + (lane<<3)]);       \
    _Pragma("unroll")                                                           \
    for (int kc=0; kc<16; ++kc){                                                \
      short8 a0_ = ab_[kc&3][0], a1_ = ab_[kc&3][1];                            \
      if (kc < 12){                                                             \
        int c_ = (kc + 4 + rot) & 15;                                           \
        ab_[kc&3][0] = *(const short8*)(ap0_ + c_*32);                          \
        ab_[kc&3][1] = *(const short8*)(ap1_ + c_*32);                          \
      }                                                                         \
      if (kc < 15){                                                             \
        int c_ = (kc + 1 + rot) & 15;                                           \
        _Pragma("unroll")                                                       \
        for (int g=0; g<3; ++g)                                                 \
          bb_[(kc+1)&1][g] = *(const short8*)(&wlds[((g*16 + c_)<<9) + (lane<<3)]); \
      }                                                                         \
      _Pragma("unroll")                                                         \
      for (int g=0; g<3; ++g){                                                  \
        short8 bw_ = bb_[kc&1][g];                                              \
        ACC[g][0] = __builtin_amdgcn_mfma_f32_16x16x32_bf16(a0_, bw_, ACC[g][0], 0,0,0); \
        ACC[g][1] = __builtin_amdgcn_mfma_f32_16x16x32_bf16(a1_, bw_, ACC[g][1], 0,0,0); \
      }                                                                         \
    }                                                                           \
  } while(0)

  // h-GEMM: owner-major 16-col chunks; K32 chunk c spans owner chunks {2c,2c+1}.
  #define GEMM16H(HCB, ACC) do {                                                \
    _Pragma("unroll")                                                           \
    for (int g=0; g<3; ++g){ ACC[g][0] = (f32x4){0.f,0.f,0.f,0.f};              \
                             ACC[g][1] = (f32x4){0.f,0.f,0.f,0.f}; }            \
    const short* hp0_ = (HCB) + (quad>>1)*4096 + (wrow*32 + l16)*16 + (quad&1)*8;\
    const short* hp1_ = hp0_ + 256;                                             \
    short8 ab_[4][2];                                                           \
    _Pragma("unroll")                                                           \
    for (int d=0; d<4; ++d){                                                    \
      int c_ = (d + rot) & 15;                                                  \
      ab_[d][0] = *(const short8*)(hp0_ + c_*8192);                             \
      ab_[d][1] = *(const short8*)(hp1_ + c_*8192);                             \
    }                                                                           \
    short8 bb_[2][3];                                                           \
    _Pragma("unroll")                                                           \
    for (int g=0; g<3; ++g)                                                     \
      bb_[0][g] = *(const short8*)(&wlds[(((3+g)*16 + rot)<<9) + (lane<<3)]);   \
    _Pragma("unroll")                                                           \
    for (int kc=0; kc<16; ++kc){                                                \
      short8 a0_ = ab_[kc&3][0], a1_ = ab_[kc&3][1];                            \
      if (kc < 12){                                                             \
        int c_ = (kc + 4 + rot) & 15;                                           \
        ab_[kc&3][0] = *(const short8*)(hp0_ + c_*8192);                        \
        ab_[kc&3][1] = *(const short8*)(hp1_ + c_*8192);                        \
      }                                                                         \
      if (kc < 15){                                                             \
        int c_ = (kc + 1 + rot) & 15;                                           \
        _Pragma("unroll")                                                       \
        for (int g=0; g<3; ++g)                                                 \
          bb_[(kc+1)&1][g] = *(const short8*)(&wlds[(((3+g)*16 + c_)<<9) + (lane<<3)]); \
      }                                                                         \
      _Pragma("unroll")                                                         \
      for (int g=0; g<3; ++g){                                                  \
        short8 bw_ = bb_[kc&1][g];                                              \
        ACC[g][0] = __builtin_amdgcn_mfma_f32_16x16x32_bf16(a0_, bw_, ACC[g][0], 0,0,0); \
        ACC[g][1] = __builtin_amdgcn_mfma_f32_16x16x32_bf16(a1_, bw_, ACC[g][1], 0,0,0); \
      }                                                                         \
    }                                                                           \
  } while(0)

  if (wid < 8){
    // ================= PRODUCER role: gi(t) -> LDS ring slot t&1 =================
    for (int t = 0; t < 64; ++t){
      if (t >= 2){
        // WAR: consumers must have finished reading gi(t-2) from this slot
        unsigned tgt = 8u * (unsigned)(t >> 1);
        int g_ = 0;
        while (__hip_atomic_load(&gcons[t & 1], __ATOMIC_ACQUIRE,
                                 __HIP_MEMORY_SCOPE_WORKGROUP) < tgt){
          __builtin_amdgcn_s_sleep(1);
          if (++g_ > 8000000) break;
        }
      }
      f32x4 acc[3][2];
      const short* xb_ = (const short*)(x_seq +
          ((size_t)(t*NC + k)*Bdim + bt*256)*Hdim);
      GEMM16X(xb_, acc);
      // pack f32x4 -> 4 bf16, one 8B LDS write per (g,rb)
      int gbase = (t & 1)*12288;
      #pragma unroll
      for (int g = 0; g < 3; ++g){
        #pragma unroll
        for (int rb = 0; rb < 2; ++rb){
          unsigned lo = ((unsigned)(unsigned short)f2bf_(acc[g][rb][0])) |
                        (((unsigned)(unsigned short)f2bf_(acc[g][rb][1])) << 16);
          unsigned hi = ((unsigned)(unsigned short)f2bf_(acc[g][rb][2])) |
                        (((unsigned)(unsigned short)f2bf_(acc[g][rb][3])) << 16);
          int idx = gbase + (((g*2 + rb)*8 + wrow)*64 + lane)*4;
          int2 pk; pk.x = (int)lo; pk.y = (int)hi;
          *(int2*)(&glds[idx]) = pk;
        }
      }
      if (lane == 0)
        __hip_atomic_fetch_add(&gprod[t & 1], 1u,
                               __ATOMIC_RELEASE, __HIP_MEMORY_SCOPE_WORKGROUP);
    }
  } else {
    // ================= CONSUMER role: recurrence for o-tile j =================
    for (int s = 0; s < 64; ++s){
      const bf16* h_in  = (s & 1) ? h_b0 : h_b1;
      bf16*       h_out = (s & 1) ? h_b1 : h_b0;

      // cross-CU rendezvous: wave 8 polls the 32 group flags, broadcasts via LDS
      if (wid == 8){
        int g_ = 0;
        for (;;){
          unsigned v_ = 0xFFFFFFFFu;
          if (lane < 32)
            v_ = __hip_atomic_load(&gflags[lane], __ATOMIC_RELAXED,
                                   __HIP_MEMORY_SCOPE_AGENT);
          if (__ballot(v_ >= (unsigned)s) == ~0ull) break;
          __builtin_amdgcn_s_sleep(1);
          if (++g_ > 8000000) break;
        }
        if (lane == 0)
          __hip_atomic_store(&hready, (unsigned)(s + 1),
                             __ATOMIC_RELEASE, __HIP_MEMORY_SCOPE_WORKGROUP);
      } else {
        int g_ = 0;
        while (__hip_atomic_load(&hready, __ATOMIC_ACQUIRE,
                                 __HIP_MEMORY_SCOPE_WORKGROUP) < (unsigned)(s + 1)){
          __builtin_amdgcn_s_sleep(1);
          if (++g_ > 8000000) break;
        }
      }

      f32x4 hacc[3][2];
      __builtin_amdgcn_s_setprio(1);
      GEMM16H((const short*)h_in + hgbase, hacc);
      __builtin_amdgcn_s_setprio(0);

      // gi(s) from LDS ring (producers run ~1 step ahead; near-instant)
      {
        unsigned tgt = 8u * (unsigned)((s >> 1) + 1);
        int g_ = 0;
        while (__hip_atomic_load(&gprod[s & 1], __ATOMIC_ACQUIRE,
                                 __HIP_MEMORY_SCOPE_WORKGROUP) < tgt){
          __builtin_amdgcn_s_sleep(1);
          if (++g_ > 8000000) break;
        }
      }
      int2 gvp[3][2];      // packed gi: 12 VGPRs, unpacked per-use in epilogue
      {
        int gbase = (s & 1)*12288;
        #pragma unroll
        for (int g = 0; g < 3; ++g)
          #pragma unroll
          for (int rb = 0; rb < 2; ++rb)
            gvp[g][rb] = *(const int2*)(&glds[gbase + (((g*2 + rb)*8 + wrow)*64 + lane)*4]);
      }
      // gi reads complete -> free the ring slot now (epilogue off the WAR chain)
      asm volatile("s_waitcnt lgkmcnt(0)" ::: "memory");
      if (lane == 0)
        __hip_atomic_fetch_add(&gcons[s & 1], 1u,
                               __ATOMIC_RELEASE, __HIP_MEMORY_SCOPE_WORKGROUP);

      // gates, register h update, h store
      bf16* hob = h_out + hgbase + (size_t)j*4096;
      #pragma unroll
      for (int rb = 0; rb < 2; ++rb){
        #pragma unroll
        for (int reg = 0; reg < 4; ++reg){
          int bl = wrow*32 + rb*16 + quad*4 + reg;
          unsigned ur = (unsigned)((reg & 2) ? gvp[0][rb].y : gvp[0][rb].x);
          unsigned uz = (unsigned)((reg & 2) ? gvp[1][rb].y : gvp[1][rb].x);
          unsigned un = (unsigned)((reg & 2) ? gvp[2][rb].y : gvp[2][rb].x);
          float gir = bf2f_((short)((reg & 1) ? (ur >> 16) : (ur & 0xFFFF)));
          float giz = bf2f_((short)((reg & 1) ? (uz >> 16) : (uz & 0xFFFF)));
          float gin = bf2f_((short)((reg & 1) ? (un >> 16) : (un & 0xFFFF)));
          float r = sigmoidf_(gir + hacc[0][rb][reg] + br);
          float z = sigmoidf_(giz + hacc[1][rb][reg] + bz);
          float n = tanhf_(gin + bnx + r*(hacc[2][rb][reg] + bnh));
          float hn = (1.f - z)*n + z*hk[rb][reg];
          hk[rb][reg] = hn;
          hob[bl*16 + l16] = (bf16)hn;
        }
      }

      // per-wave store drain; last-arriving wave bumps the group flag
      asm volatile("s_waitcnt vmcnt(0)" ::: "memory");
      if (lane == 0){
        unsigned old = __hip_atomic_fetch_add(&hdone, 1u,
                          __ATOMIC_ACQ_REL, __HIP_MEMORY_SCOPE_WORKGROUP);
        if (old == (unsigned)(8*s + 7))
          __hip_atomic_fetch_add(&gflags[j], 1u,
                                 __ATOMIC_RELAXED, __HIP_MEMORY_SCOPE_AGENT);
      }

      // off-critical-path: output head partial dot
      int tmap = (k < 2) ? s : (Tdim - 1 - s);
      #pragma unroll
      for (int rb = 0; rb < 2; ++rb){
        #pragma unroll
        for (int reg = 0; reg < 4; ++reg){
          int bl = wrow*32 + rb*16 + quad*4 + reg;
          float v = hk[rb][reg]*wout;
          v += __shfl_xor(v, 1, 64);
          v += __shfl_xor(v, 2, 64);
          v += __shfl_xor(v, 4, 64);
          v += __shfl_xor(v, 8, 64);
          if (l16 == 0)
            __builtin_nontemporal_store(v,
              &part[((size_t)(k*Tdim + tmap)*Bdim + bt*256 + bl)*32 + j]);
        }
      }
    }
  }
  #undef GEMM16X
  #undef GEMM16H
}

// ---------------- out[head][b][t] = bias + sum over {head,head+2} x 32 j-partials ----
// part layout [K][T][B][32]: per-thread reads are 128 B contiguous.
__global__ __launch_bounds__(256) void finalize_kernel(const float* __restrict__ part,
                                const float* __restrict__ fc_out_b, float* __restrict__ out){
  int idx = blockIdx.x*256 + threadIdx.x;  // 0..65535
  int head = idx >> 15;
  int b = (idx >> 6) & 511;
  int t = idx & 63;
  float v = fc_out_b[head];
  #pragma unroll
  for (int kk = 0; kk < 2; ++kk){
    const float4* p = (const float4*)(part +
        ((size_t)((head + kk*2)*Tdim + t)*Bdim + b)*32);
    #pragma unroll
    for (int jj = 0; jj < 8; ++jj){
      float4 q = p[jj];
      v += q.x + q.y + q.z + q.w;
    }
  }
  out[idx] = v;
}

extern "C" void kernel_launch(void* const* d_in, const int* in_sizes, int n_in,
                              void* d_out, int out_size, void* d_ws, size_t ws_size,
                              hipStream_t stream){
  (void)in_sizes; (void)n_in; (void)out_size; (void)ws_size;
  const float* data     = (const float*)d_in[0];
  const float* init_h   = (const float*)d_in[1];
  const float* fc_in_W  = (const float*)d_in[2];
  const float* fc_in_b  = (const float*)d_in[3];
  const float* Wih      = (const float*)d_in[4];
  const float* Whh      = (const float*)d_in[5];
  const float* bih      = (const float*)d_in[6];
  const float* bhh      = (const float*)d_in[7];
  const float* fc_out_W = (const float*)d_in[8];
  const float* fc_out_b = (const float*)d_in[9];
  float* out = (float*)d_out;

  char* ws = (char*)d_ws;
  bf16*  x_seq   = (bf16*)ws;                     // [T][K][B][H] bf16 : 134217728 B
  bf16*  h_b0    = (bf16*)(ws + 134217728);       // [grp*32+c][b][16] :  2097152 B
  bf16*  h_b1    = (bf16*)(ws + 136314880);       //                      2097152 B
  float* part    = (float*)(ws + 138412032);      // [K][T][B][32] f32: 16777216 B
  bf16*  dataT   = (bf16*)(ws + 138412032);       // overlay (dead before rnn): 4 MB
  bf16*  fcW_bf  = (bf16*)(ws + 165675008);       // [K][H][F] bf16 :      262144 B
  unsigned* flags= (unsigned*)(ws + 165937152);   // [8][32] u32 = 1024 B
  unsigned* xslot= (unsigned*)(ws + 165938176);   // [8][32] u32 = 1024 B

  const int nFW = NC*Hdim*Fdim;     // 131,072
  hipLaunchKernelGGL(pack_kernel, dim3(nFW/1024), dim3(256), 0, stream, fc_in_W, fcW_bf, nFW);
  hipLaunchKernelGGL(init_kernel, dim3(4096), dim3(256), 0, stream, init_h, h_b1, flags);
  hipLaunchKernelGGL(transpose_kernel, dim3(512), dim3(256), 0, stream, data, dataT);
  hipLaunchKernelGGL(proj_kernel, dim3(8192), dim3(256), 0, stream, dataT, fcW_bf, fc_in_b, x_seq);
  hipLaunchKernelGGL(rnn_kernel, dim3(256), dim3(1024), 0, stream,
      x_seq, init_h, h_b0, h_b1, Wih, Whh, bih, bhh, fc_out_W, part, flags, xslot);
  hipLaunchKernelGGL(finalize_kernel, dim3(256), dim3(256), 0, stream, part, fc_out_b, out);
}